// Round 4
// baseline (1159.386 us; speedup 1.0000x reference)
//
#include <hip/hip_runtime.h>
#include <math.h>

#define DIMX 50
#define KK   51
#define NE   6
#define NB   8
#define NVOX ((size_t)NB * NE * DIMX * DIMX * DIMX)  // 6,000,000

// ---------------- taps: per-element 1D Gaussian + global-sum scale ----------------
__global__ void taps_kernel(const float* __restrict__ sigma,
                            float* __restrict__ g,   // E*51 raw 1D gaussian
                            float* __restrict__ gs,  // E*51 scaled (a_e/S folded in)
                            float* __restrict__ maxval) {
    __shared__ float sg[NE * KK];
    __shared__ float ssum[NE];
    int t = threadIdx.x;
    if (t == 0) *maxval = 0.f;
    if (t < NE * KK) {
        int e = t / KK, i = t % KK;
        float d = (float)i - 25.0f;
        float var = sigma[e] * sigma[e];
        float val = expf(-d * d / (2.f * var));
        sg[t] = val;
        g[t] = val;
    }
    __syncthreads();
    if (t < NE) {
        float s = 0.f;
        for (int i = 0; i < KK; ++i) s += sg[t * KK + i];
        ssum[t] = s;
    }
    __syncthreads();
    if (t < NE * KK) {
        int e = t / KK;
        float S = 0.f;
        for (int e2 = 0; e2 < NE; ++e2) {
            float var2 = sigma[e2] * sigma[e2];
            float a2 = 1.f / (2.f * (float)M_PI * var2);
            float se = ssum[e2];
            S += a2 * se * se * se;
        }
        float var = sigma[e] * sigma[e];
        float a = 1.f / (2.f * (float)M_PI * var);
        gs[t] = sg[t] * (a / S);
    }
}

// ---------------- blur: 4 outputs per thread along the blur axis ----------------
// AXIS: 0=w (stride 1), 1=h (stride 50), 2=d (stride 2500, fused global max)
template <int AXIS, bool DOMAX>
__global__ void blur4(const float* __restrict__ in, float* __restrict__ out,
                      const float* __restrict__ taps, float* __restrict__ maxval) {
    __shared__ float st[NE * KK];
    for (int i = threadIdx.x; i < NE * KK; i += 256) st[i] = taps[i];
    __syncthreads();
    constexpr int G = 13;                       // ceil(50/4)
    constexpr long STRIDE = (AXIS == 0) ? 1 : (AXIS == 1) ? DIMX : (long)DIMX * DIMX;
    const size_t total = (size_t)NB * NE * DIMX * DIMX * G;
    size_t idx0 = (size_t)blockIdx.x * 256 + threadIdx.x;
    const bool live = idx0 < total;
    size_t idx = live ? idx0 : (total - 1);
    int w = 0, h = 0, d = 0, gidx; size_t be;
    if (AXIS == 0)      { gidx = (int)(idx % G); size_t r = idx / G;    h = (int)(r % DIMX); d = (int)((r / DIMX) % DIMX); be = r / ((size_t)DIMX * DIMX); }
    else if (AXIS == 1) { w = (int)(idx % DIMX); size_t r = idx / DIMX; gidx = (int)(r % G); d = (int)((r / G) % DIMX);   be = r / ((size_t)G * DIMX); }
    else                { w = (int)(idx % DIMX); size_t r = idx / DIMX; h = (int)(r % DIMX); gidx = (int)((r / DIMX) % G); be = r / ((size_t)DIMX * G); }
    const int e = (int)(be % NE);
    const float* tp = &st[e * KK];
    long base;
    if (AXIS == 0)      base = (((long)be * DIMX + d) * DIMX + h) * DIMX;
    else if (AXIS == 1) base = (((long)be * DIMX + d) * DIMX) * DIMX + w;
    else                base = (((long)be * DIMX) * DIMX + h) * DIMX + w;

    float acc[4] = {0.f, 0.f, 0.f, 0.f};
#pragma unroll
    for (int j = 0; j < 54; ++j) {
        int c = 4 * gidx + j - 25;
        float v = (live && (unsigned)c < DIMX) ? in[base + (long)c * STRIDE] : 0.f;
#pragma unroll
        for (int k = 0; k < 4; ++k) {
            int tj = j - k;
            if (tj >= 0 && tj < KK) acc[k] = fmaf(tp[tj], v, acc[k]);
        }
    }
    float m = 0.f;
#pragma unroll
    for (int k = 0; k < 4; ++k) {
        int p = 4 * gidx + k;
        if (live && p < DIMX) {
            out[base + (long)p * STRIDE] = acc[k];
            if (DOMAX) m = fmaxf(m, acc[k]);
        }
    }
    if (DOMAX) {
        for (int o = 32; o; o >>= 1) m = fmaxf(m, __shfl_xor(m, o));
        if ((threadIdx.x & 63) == 0) atomicMax((int*)maxval, __float_as_int(m));
    }
}

// ---------------- wave-autonomous fused conv3x3x3 [+pool2+bias+relu | partial] ----------------
// One wave = (b, 4^3 pooled tile, 4 consecutive co). Private double-buffered 10^3 window
// in LDS; no block barriers — only per-ci lgkmcnt(0). Weights via wave-uniform s_loads.
template <int CIN, int CINTOT, int DIN, int DP, bool DIV, bool PARTIAL>
__global__ __launch_bounds__(256, 4)
void conv_wave(const float* __restrict__ in, const float* __restrict__ w,
               const float* __restrict__ bias, const float* __restrict__ maxval,
               float* __restrict__ out, int COUT) {
    constexpr int NT  = (DP + 3) / 4;
    constexpr int NT3 = NT * NT * NT;
    constexpr int WSZ = 1000;                  // 10x10x10 window
    __shared__ float lds[4][2][WSZ];

    const int t    = threadIdx.x;
    const int lane = t & 63;
    const int wv   = __builtin_amdgcn_readfirstlane(t >> 6);
    const int px = lane & 3, py = (lane >> 2) & 3, pz = lane >> 4;

    const int tile  = blockIdx.x % NT3;
    const int chunk = blockIdx.x / NT3;
    const int tx = tile % NT, ty = (tile / NT) % NT, tz = tile / (NT * NT);
    const int b    = blockIdx.z;
    const int co0  = (blockIdx.y * 4 + wv) * 4;      // wave-uniform
    const int ci_base = chunk * CIN;

    const float* ib = in + ((size_t)b * CINTOT + ci_base) * (DIN * DIN * DIN);
    const float* wb = w + ((size_t)co0 * CINTOT + ci_base) * 27;
    const int ox0 = 8 * tx, oy0 = 8 * ty, oz0 = 8 * tz;

    // precompute global spatial offsets for staging (16 per lane)
    int voff[16];
#pragma unroll
    for (int s = 0; s < 16; ++s) {
        int j = lane + 64 * s; if (j > WSZ - 1) j = WSZ - 1;
        int z = j / 100, r = j % 100, y = r / 10, x = r % 10;
        int gz = oz0 + z; if (gz > DIN - 1) gz = DIN - 1;
        int gy = oy0 + y; if (gy > DIN - 1) gy = DIN - 1;
        int gx = ox0 + x; if (gx > DIN - 1) gx = DIN - 1;
        voff[s] = (gz * DIN + gy) * DIN + gx;
    }
    float* lb[2] = { &lds[wv][0][0], &lds[wv][1][0] };
    const int jtail = (lane + 960 > WSZ - 1) ? (WSZ - 1) : (lane + 960);

    float acc[4][8];
#pragma unroll
    for (int c = 0; c < 4; ++c)
#pragma unroll
        for (int i = 0; i < 8; ++i) acc[c][i] = 0.f;

    // prolog: stage ci=0
    {
        float val[16];
#pragma unroll
        for (int s = 0; s < 16; ++s) val[s] = ib[voff[s]];
#pragma unroll
        for (int s = 0; s < 15; ++s) lb[0][lane + 64 * s] = val[s];
        lb[0][jtail] = val[15];
        __builtin_amdgcn_wave_barrier();
        asm volatile("s_waitcnt lgkmcnt(0)" ::: "memory");
        __builtin_amdgcn_sched_barrier(0);
    }

    for (int ci = 0; ci < CIN; ++ci) {
        float* cur = lb[ci & 1];
        float val[16];
        if (ci + 1 < CIN) {
            const float* nb = ib + (size_t)(ci + 1) * (DIN * DIN * DIN);
#pragma unroll
            for (int s = 0; s < 16; ++s) val[s] = nb[voff[s]];
        }
#pragma unroll
        for (int dz = 0; dz < 4; ++dz) {
            float sl[4][4];
            const float* sb = cur + (2 * pz + dz) * 100 + 2 * py * 10 + 2 * px;
#pragma unroll
            for (int dy = 0; dy < 4; ++dy) {
                float2 a0 = *(const float2*)(sb + dy * 10);
                float2 a1 = *(const float2*)(sb + dy * 10 + 2);
                sl[dy][0] = a0.x; sl[dy][1] = a0.y; sl[dy][2] = a1.x; sl[dy][3] = a1.y;
            }
#pragma unroll
            for (int c = 0; c < 4; ++c) {
#pragma unroll
                for (int oz = 0; oz < 2; ++oz) {
                    const int kz = dz - oz;
                    if (kz < 0 || kz > 2) continue;
                    const float* wc = wb + ((size_t)c * CINTOT + ci) * 27 + kz * 9;
#pragma unroll
                    for (int ky = 0; ky < 3; ++ky)
#pragma unroll
                        for (int kx = 0; kx < 3; ++kx) {
                            float wvv = wc[ky * 3 + kx];
#pragma unroll
                            for (int oy = 0; oy < 2; ++oy)
#pragma unroll
                                for (int ox = 0; ox < 2; ++ox)
                                    acc[c][oz * 4 + oy * 2 + ox] =
                                        fmaf(wvv, sl[oy + ky][ox + kx], acc[c][oz * 4 + oy * 2 + ox]);
                        }
                }
            }
        }
        if (ci + 1 < CIN) {
            float* nxt = lb[(ci + 1) & 1];
#pragma unroll
            for (int s = 0; s < 15; ++s) nxt[lane + 64 * s] = val[s];
            nxt[jtail] = val[15];
            __builtin_amdgcn_wave_barrier();
            asm volatile("s_waitcnt lgkmcnt(0)" ::: "memory");
            __builtin_amdgcn_sched_barrier(0);
        }
    }

    if constexpr (PARTIAL) {
#pragma unroll
        for (int c = 0; c < 4; ++c) {
            size_t base = (((size_t)chunk * NB + b) * (size_t)COUT + (co0 + c)) * 512 + (size_t)lane * 8;
#pragma unroll
            for (int i = 0; i < 8; ++i) out[base + i] = acc[c][i];
        }
    } else {
        const int qx = tx * 4 + px, qy = ty * 4 + py, qz = tz * 4 + pz;
        if (qx < DP && qy < DP && qz < DP) {
            float mv = DIV ? *maxval : 1.f;
#pragma unroll
            for (int c = 0; c < 4; ++c) {
                float m = acc[c][0];
#pragma unroll
                for (int i = 1; i < 8; ++i) m = fmaxf(m, acc[c][i]);
                float o = DIV ? (m / mv + bias[co0 + c]) : (m + bias[co0 + c]);
                out[((size_t)b * COUT + (co0 + c)) * (DP * DP * DP) + (qz * DP + qy) * DP + qx] =
                    fmaxf(o, 0.f);
            }
        }
    }
}

// ---------------- conv3 chunk-reduce + pool + bias + relu ----------------
template <int NCH>
__global__ void pool3_kernel(const float* __restrict__ part, const float* __restrict__ bias,
                             float* __restrict__ out) {
    int idx = blockIdx.x * 256 + threadIdx.x;  // 8*128*64
    if (idx >= NB * 128 * 64) return;
    int vox = idx & 63;
    int co  = (idx >> 6) & 127;
    int b   = idx >> 13;
    float s[8];
#pragma unroll
    for (int i = 0; i < 8; ++i) s[i] = 0.f;
#pragma unroll
    for (int ch = 0; ch < NCH; ++ch) {
        const float* p = part + (((size_t)ch * NB + b) * 128 + co) * 512 + (size_t)vox * 8;
#pragma unroll
        for (int i = 0; i < 8; ++i) s[i] += p[i];
    }
    float m = s[0];
#pragma unroll
    for (int i = 1; i < 8; ++i) m = fmaxf(m, s[i]);
    out[((size_t)b * 128 + co) * 64 + vox] = fmaxf(m + bias[co], 0.f);
}

// ---------------- conv4: Cin=128, Din=4 -> conv 2^3 -> pool 1; wave per (b,co) ----------------
__global__ void conv4_kernel(const float* __restrict__ in, const float* __restrict__ w,
                             const float* __restrict__ bias, float* __restrict__ out) {
    int wid = (int)((blockIdx.x * blockDim.x + threadIdx.x) >> 6);
    int lane = threadIdx.x & 63;
    if (wid >= NB * 256) return;
    int b = wid >> 8, co = wid & 255;
    float acc[8];
#pragma unroll
    for (int i = 0; i < 8; ++i) acc[i] = 0.f;
    for (int half = 0; half < 2; ++half) {
        int ci = lane + half * 64;
        const float* cb = in + ((size_t)b * 128 + ci) * 64;
        float win[64];
        const float4* c4 = (const float4*)cb;
#pragma unroll
        for (int i = 0; i < 16; ++i) {
            float4 v = c4[i];
            win[4 * i + 0] = v.x; win[4 * i + 1] = v.y;
            win[4 * i + 2] = v.z; win[4 * i + 3] = v.w;
        }
        const float* wc = w + ((size_t)co * 128 + ci) * 27;
        float wr[27];
#pragma unroll
        for (int i = 0; i < 27; ++i) wr[i] = wc[i];
#pragma unroll
        for (int kz = 0; kz < 3; ++kz)
#pragma unroll
            for (int ky = 0; ky < 3; ++ky)
#pragma unroll
                for (int kx = 0; kx < 3; ++kx) {
                    float wv = wr[(kz * 3 + ky) * 3 + kx];
#pragma unroll
                    for (int oz = 0; oz < 2; ++oz)
#pragma unroll
                        for (int oy = 0; oy < 2; ++oy)
#pragma unroll
                            for (int ox = 0; ox < 2; ++ox)
                                acc[(oz * 2 + oy) * 2 + ox] =
                                    fmaf(wv, win[((oz + kz) * 4 + (oy + ky)) * 4 + ox + kx],
                                         acc[(oz * 2 + oy) * 2 + ox]);
                }
    }
#pragma unroll
    for (int o = 32; o; o >>= 1)
#pragma unroll
        for (int i = 0; i < 8; ++i) acc[i] += __shfl_xor(acc[i], o);
    if (lane == 0) {
        float m = acc[0];
#pragma unroll
        for (int i = 1; i < 8; ++i) m = fmaxf(m, acc[i]);
        out[(size_t)b * 256 + co] = fmaxf(m + bias[co], 0.f);
    }
}

// ---------------- FC head: (8,256) -> relu(128) -> 29 ----------------
__global__ void head_kernel(const float* __restrict__ v,
                            const float* __restrict__ fw1, const float* __restrict__ fb1,
                            const float* __restrict__ fw2, const float* __restrict__ fb2,
                            float* __restrict__ out) {
    int b = blockIdx.x, t = threadIdx.x;
    __shared__ float sv[256];
    __shared__ float s1[128];
    sv[t] = v[b * 256 + t];
    sv[t + 128] = v[b * 256 + t + 128];
    __syncthreads();
    float acc = fb1[t];
    const float* wr = fw1 + t * 256;
    for (int k = 0; k < 256; ++k) acc = fmaf(wr[k], sv[k], acc);
    s1[t] = fmaxf(acc, 0.f);
    __syncthreads();
    if (t < 29) {
        float a2 = fb2[t];
        const float* w2 = fw2 + t * 128;
        for (int k = 0; k < 128; ++k) a2 = fmaf(w2[k], s1[k], a2);
        out[b * 29 + t] = a2;
    }
}

extern "C" void kernel_launch(void* const* d_in, const int* in_sizes, int n_in,
                              void* d_out, int out_size, void* d_ws, size_t ws_size,
                              hipStream_t stream) {
    const float* x     = (const float*)d_in[0];
    const float* sigma = (const float*)d_in[1];
    const float* w1    = (const float*)d_in[2];
    const float* b1    = (const float*)d_in[3];
    const float* w2    = (const float*)d_in[4];
    const float* b2    = (const float*)d_in[5];
    const float* w3    = (const float*)d_in[6];
    const float* b3    = (const float*)d_in[7];
    const float* w4    = (const float*)d_in[8];
    const float* b4    = (const float*)d_in[9];
    const float* fw1   = (const float*)d_in[10];
    const float* fb1   = (const float*)d_in[11];
    const float* fw2   = (const float*)d_in[12];
    const float* fb2   = (const float*)d_in[13];
    float* out = (float*)d_out;

    float* A  = (float*)d_ws;          // 6,000,000 floats
    float* Bf = A + NVOX;              // 6,000,000 floats
    float* g  = Bf + NVOX;             // 306
    float* gs = g + NE * KK;           // 306
    float* mx = gs + NE * KK;          // 1

    taps_kernel<<<1, 512, 0, stream>>>(sigma, g, gs, mx);

    const size_t tot4 = (size_t)NB * NE * DIMX * DIMX * 13;
    int nblk4 = (int)((tot4 + 255) / 256);
    blur4<0, false><<<nblk4, 256, 0, stream>>>(x,  A,  g,  nullptr);
    blur4<1, false><<<nblk4, 256, 0, stream>>>(A,  Bf, g,  nullptr);
    blur4<2, true> <<<nblk4, 256, 0, stream>>>(Bf, A,  gs, mx);   // fused global max

    // conv1: (8,6,50^3) -> (8,32,24^3), /max folded into epilogue
    conv_wave<6, 6, 50, 24, true, false><<<dim3(216, 2, 8), 256, 0, stream>>>(A, w1, b1, mx, Bf, 32);
    // conv2: (8,32,24^3) -> (8,64,11^3)
    conv_wave<32, 32, 24, 11, false, false><<<dim3(27, 4, 8), 256, 0, stream>>>(Bf, w2, b2, nullptr, A, 64);
    // conv3: (8,64,11^3) -> partials over 8 ci-chunks (into Bf region, conv2 input dead)
    float* part = Bf;                                  // 8*8*128*512 = 4,194,304 floats
    float* pooled3 = Bf + 8 * NB * 128 * 512;          // 8*128*64 floats
    conv_wave<8, 64, 11, 4, false, true><<<dim3(8, 8, 8), 256, 0, stream>>>(A, w3, b3, nullptr, part, 128);
    pool3_kernel<8><<<256, 256, 0, stream>>>(part, b3, pooled3);
    // conv4: (8,128,4^3) -> (8,256)  (write into A; conv3 input dead)
    float* v4 = A;
    conv4_kernel<<<512, 256, 0, stream>>>(pooled3, w4, b4, v4);
    // head
    head_kernel<<<8, 128, 0, stream>>>(v4, fw1, fb1, fw2, fb2, out);
}

// Round 5
// 753.914 us; speedup vs baseline: 1.5378x; 1.5378x over previous
//
#include <hip/hip_runtime.h>
#include <math.h>

#define DIMX 50
#define KK   51
#define NE   6
#define NB   8
#define NVOX ((size_t)NB * NE * DIMX * DIMX * DIMX)  // 6,000,000
#define MP   52                                      // padded M stride

// ---------------- taps + blur matrices: M[m][e][o][c] = tap_m,e[c-o+25] ----------------
__global__ void taps_kernel(const float* __restrict__ sigma,
                            float* __restrict__ M0,  // raw taps matrix  (NE*52*52)
                            float* __restrict__ M1,  // scaled taps matrix
                            float* __restrict__ maxval) {
    __shared__ float sg[NE * KK];
    __shared__ float sgs[NE * KK];
    __shared__ float ssum[NE];
    int t = threadIdx.x;
    if (t == 0) *maxval = 0.f;
    if (t < NE * KK) {
        int e = t / KK, i = t % KK;
        float d = (float)i - 25.0f;
        float var = sigma[e] * sigma[e];
        sg[t] = expf(-d * d / (2.f * var));
    }
    __syncthreads();
    if (t < NE) {
        float s = 0.f;
        for (int i = 0; i < KK; ++i) s += sg[t * KK + i];
        ssum[t] = s;
    }
    __syncthreads();
    if (t < NE * KK) {
        int e = t / KK;
        float S = 0.f;
        for (int e2 = 0; e2 < NE; ++e2) {
            float var2 = sigma[e2] * sigma[e2];
            float a2 = 1.f / (2.f * (float)M_PI * var2);
            float se = ssum[e2];
            S += a2 * se * se * se;
        }
        float var = sigma[e] * sigma[e];
        float a = 1.f / (2.f * (float)M_PI * var);
        sgs[t] = sg[t] * (a / S);
    }
    __syncthreads();
    for (int i = t; i < 2 * NE * MP * MP; i += 512) {
        int c = i % MP, o = (i / MP) % MP, e = (i / (MP * MP)) % NE, m = i / (MP * MP * NE);
        int j = c - o + 25;
        float v = 0.f;
        if (o < 50 && c < 50 && j >= 0 && j < KK) v = (m == 0 ? sg : sgs)[e * KK + j];
        (m == 0 ? M0 : M1)[(e * MP + o) * MP + c] = v;
    }
}

// ---------------- blur pass as per-plane 50x50 matmul ----------------
// AXIS = contracted axis (2=d, 1=h, 0=w). Block = one (be, f) plane.
// LDS holds plane [c][r]; lanes = r; M rows read wave-uniformly (scalar pipe).
template <int AXIS, bool DOMAX>
__global__ __launch_bounds__(256, 8)
void blur_mm(const float* __restrict__ in, float* __restrict__ out,
             const float* __restrict__ M, float* __restrict__ maxval) {
    __shared__ float sp[50][MP];
    const int t  = threadIdx.x;
    const int f  = blockIdx.x % 50;
    const int be = blockIdx.x / 50;
    const int e  = be % NE;
    const float* base = in + (size_t)be * 125000;
    for (int i = t; i < 2500; i += 256) {
        int hi = i / 50, lo = i % 50;
        if (AXIS == 2)      sp[hi][lo] = base[hi * 2500 + f * 50 + lo];
        else if (AXIS == 1) sp[hi][lo] = base[f * 2500 + hi * 50 + lo];
        else                sp[lo][hi] = base[f * 2500 + hi * 50 + lo];
    }
    __syncthreads();
    const int lane = t & 63;
    const int lr   = lane < 50 ? lane : 49;
    const int wv   = __builtin_amdgcn_readfirstlane(t >> 6);
    float* ob = out + (size_t)be * 125000;
    const float* Me = M + (size_t)e * MP * MP;
    float m = 0.f;
    for (int g = wv; g < 13; g += 4) {
        const int o0 = g * 4;
        const float* Mr0 = Me + (o0 + 0) * MP;
        const float* Mr1 = Me + (o0 + 1) * MP;
        const float* Mr2 = Me + (o0 + 2) * MP;
        const float* Mr3 = Me + (o0 + 3) * MP;
        float a0 = 0.f, a1 = 0.f, a2 = 0.f, a3 = 0.f;
#pragma unroll 10
        for (int c = 0; c < 50; ++c) {
            float v = sp[c][lr];
            a0 = fmaf(Mr0[c], v, a0);
            a1 = fmaf(Mr1[c], v, a1);
            a2 = fmaf(Mr2[c], v, a2);
            a3 = fmaf(Mr3[c], v, a3);
        }
        if (lane < 50) {
            float accs[4] = {a0, a1, a2, a3};
#pragma unroll
            for (int k = 0; k < 4; ++k) {
                int o = o0 + k;
                if (o < 50) {
                    size_t addr;
                    if (AXIS == 2)      addr = (size_t)o * 2500 + f * 50 + lane;
                    else if (AXIS == 1) addr = (size_t)f * 2500 + o * 50 + lane;
                    else                addr = (size_t)f * 2500 + lane * 50 + o;
                    ob[addr] = accs[k];
                    if (DOMAX) m = fmaxf(m, accs[k]);
                }
            }
        }
    }
    if (DOMAX) {
        for (int o = 32; o; o >>= 1) m = fmaxf(m, __shfl_xor(m, o));
        if ((t & 63) == 0) atomicMax((int*)maxval, __float_as_int(m));
    }
}

// ---------------- wave-autonomous fused conv3x3x3 [+pool2+bias+relu | partial] ----------------
template <int CIN, int CINTOT, int DIN, int DP, bool DIV, bool PARTIAL>
__global__ __launch_bounds__(256, 4)
void conv_wave(const float* __restrict__ in, const float* __restrict__ w,
               const float* __restrict__ bias, const float* __restrict__ maxval,
               float* __restrict__ out, int COUT) {
    constexpr int NT  = (DP + 3) / 4;
    constexpr int NT3 = NT * NT * NT;
    constexpr int WSZ = 1000;                  // 10x10x10 window
    __shared__ float lds[4][2][WSZ];

    const int t    = threadIdx.x;
    const int lane = t & 63;
    const int wv   = __builtin_amdgcn_readfirstlane(t >> 6);
    const int px = lane & 3, py = (lane >> 2) & 3, pz = lane >> 4;

    const int tile  = blockIdx.x % NT3;
    const int chunk = blockIdx.x / NT3;
    const int tx = tile % NT, ty = (tile / NT) % NT, tz = tile / (NT * NT);
    const int b    = blockIdx.z;
    const int co0  = (blockIdx.y * 4 + wv) * 4;      // wave-uniform
    const int ci_base = chunk * CIN;

    const float* ib = in + ((size_t)b * CINTOT + ci_base) * (DIN * DIN * DIN);
    const float* wb = w + ((size_t)co0 * CINTOT + ci_base) * 27;
    const int ox0 = 8 * tx, oy0 = 8 * ty, oz0 = 8 * tz;

    int voff[16];
#pragma unroll
    for (int s = 0; s < 16; ++s) {
        int j = lane + 64 * s; if (j > WSZ - 1) j = WSZ - 1;
        int z = j / 100, r = j % 100, y = r / 10, x = r % 10;
        int gz = oz0 + z; if (gz > DIN - 1) gz = DIN - 1;
        int gy = oy0 + y; if (gy > DIN - 1) gy = DIN - 1;
        int gx = ox0 + x; if (gx > DIN - 1) gx = DIN - 1;
        voff[s] = (gz * DIN + gy) * DIN + gx;
    }
    float* lb[2] = { &lds[wv][0][0], &lds[wv][1][0] };
    const int jtail = (lane + 960 > WSZ - 1) ? (WSZ - 1) : (lane + 960);

    float acc[4][8];
#pragma unroll
    for (int c = 0; c < 4; ++c)
#pragma unroll
        for (int i = 0; i < 8; ++i) acc[c][i] = 0.f;

    {
        float val[16];
#pragma unroll
        for (int s = 0; s < 16; ++s) val[s] = ib[voff[s]];
#pragma unroll
        for (int s = 0; s < 15; ++s) lb[0][lane + 64 * s] = val[s];
        lb[0][jtail] = val[15];
        __builtin_amdgcn_wave_barrier();
        asm volatile("s_waitcnt lgkmcnt(0)" ::: "memory");
        __builtin_amdgcn_sched_barrier(0);
    }

    for (int ci = 0; ci < CIN; ++ci) {
        float* cur = lb[ci & 1];
        float val[16];
        if (ci + 1 < CIN) {
            const float* nb = ib + (size_t)(ci + 1) * (DIN * DIN * DIN);
#pragma unroll
            for (int s = 0; s < 16; ++s) val[s] = nb[voff[s]];
        }
#pragma unroll
        for (int dz = 0; dz < 4; ++dz) {
            float sl[4][4];
            const float* sb = cur + (2 * pz + dz) * 100 + 2 * py * 10 + 2 * px;
#pragma unroll
            for (int dy = 0; dy < 4; ++dy) {
                float2 q0 = *(const float2*)(sb + dy * 10);
                float2 q1 = *(const float2*)(sb + dy * 10 + 2);
                sl[dy][0] = q0.x; sl[dy][1] = q0.y; sl[dy][2] = q1.x; sl[dy][3] = q1.y;
            }
#pragma unroll
            for (int c = 0; c < 4; ++c) {
#pragma unroll
                for (int oz = 0; oz < 2; ++oz) {
                    const int kz = dz - oz;
                    if (kz < 0 || kz > 2) continue;
                    const float* wc = wb + ((size_t)c * CINTOT + ci) * 27 + kz * 9;
#pragma unroll
                    for (int ky = 0; ky < 3; ++ky)
#pragma unroll
                        for (int kx = 0; kx < 3; ++kx) {
                            float wvv = wc[ky * 3 + kx];
#pragma unroll
                            for (int oy = 0; oy < 2; ++oy)
#pragma unroll
                                for (int ox = 0; ox < 2; ++ox)
                                    acc[c][oz * 4 + oy * 2 + ox] =
                                        fmaf(wvv, sl[oy + ky][ox + kx], acc[c][oz * 4 + oy * 2 + ox]);
                        }
                }
            }
        }
        if (ci + 1 < CIN) {
            float* nxt = lb[(ci + 1) & 1];
#pragma unroll
            for (int s = 0; s < 15; ++s) nxt[lane + 64 * s] = val[s];
            nxt[jtail] = val[15];
            __builtin_amdgcn_wave_barrier();
            asm volatile("s_waitcnt lgkmcnt(0)" ::: "memory");
            __builtin_amdgcn_sched_barrier(0);
        }
    }

    if constexpr (PARTIAL) {
#pragma unroll
        for (int c = 0; c < 4; ++c) {
            size_t base = (((size_t)chunk * NB + b) * (size_t)COUT + (co0 + c)) * 512 + (size_t)lane * 8;
#pragma unroll
            for (int i = 0; i < 8; ++i) out[base + i] = acc[c][i];
        }
    } else {
        const int qx = tx * 4 + px, qy = ty * 4 + py, qz = tz * 4 + pz;
        if (qx < DP && qy < DP && qz < DP) {
            float mv = DIV ? *maxval : 1.f;
#pragma unroll
            for (int c = 0; c < 4; ++c) {
                float m = acc[c][0];
#pragma unroll
                for (int i = 1; i < 8; ++i) m = fmaxf(m, acc[c][i]);
                float o = DIV ? (m / mv + bias[co0 + c]) : (m + bias[co0 + c]);
                out[((size_t)b * COUT + (co0 + c)) * (DP * DP * DP) + (qz * DP + qy) * DP + qx] =
                    fmaxf(o, 0.f);
            }
        }
    }
}

// ---------------- conv3 chunk-reduce + pool + bias + relu ----------------
template <int NCH>
__global__ void pool3_kernel(const float* __restrict__ part, const float* __restrict__ bias,
                             float* __restrict__ out) {
    int idx = blockIdx.x * 256 + threadIdx.x;  // 8*128*64
    if (idx >= NB * 128 * 64) return;
    int vox = idx & 63;
    int co  = (idx >> 6) & 127;
    int b   = idx >> 13;
    float s[8];
#pragma unroll
    for (int i = 0; i < 8; ++i) s[i] = 0.f;
#pragma unroll
    for (int ch = 0; ch < NCH; ++ch) {
        const float* p = part + (((size_t)ch * NB + b) * 128 + co) * 512 + (size_t)vox * 8;
#pragma unroll
        for (int i = 0; i < 8; ++i) s[i] += p[i];
    }
    float m = s[0];
#pragma unroll
    for (int i = 1; i < 8; ++i) m = fmaxf(m, s[i]);
    out[((size_t)b * 128 + co) * 64 + vox] = fmaxf(m + bias[co], 0.f);
}

// ---------------- conv4: Cin=128, Din=4 -> conv 2^3 -> pool 1; wave per (b,co) ----------------
__global__ void conv4_kernel(const float* __restrict__ in, const float* __restrict__ w,
                             const float* __restrict__ bias, float* __restrict__ out) {
    int wid = (int)((blockIdx.x * blockDim.x + threadIdx.x) >> 6);
    int lane = threadIdx.x & 63;
    if (wid >= NB * 256) return;
    int b = wid >> 8, co = wid & 255;
    float acc[8];
#pragma unroll
    for (int i = 0; i < 8; ++i) acc[i] = 0.f;
    for (int half = 0; half < 2; ++half) {
        int ci = lane + half * 64;
        const float* cb = in + ((size_t)b * 128 + ci) * 64;
        float win[64];
        const float4* c4 = (const float4*)cb;
#pragma unroll
        for (int i = 0; i < 16; ++i) {
            float4 v = c4[i];
            win[4 * i + 0] = v.x; win[4 * i + 1] = v.y;
            win[4 * i + 2] = v.z; win[4 * i + 3] = v.w;
        }
        const float* wc = w + ((size_t)co * 128 + ci) * 27;
        float wr[27];
#pragma unroll
        for (int i = 0; i < 27; ++i) wr[i] = wc[i];
#pragma unroll
        for (int kz = 0; kz < 3; ++kz)
#pragma unroll
            for (int ky = 0; ky < 3; ++ky)
#pragma unroll
                for (int kx = 0; kx < 3; ++kx) {
                    float wv = wr[(kz * 3 + ky) * 3 + kx];
#pragma unroll
                    for (int oz = 0; oz < 2; ++oz)
#pragma unroll
                        for (int oy = 0; oy < 2; ++oy)
#pragma unroll
                            for (int ox = 0; ox < 2; ++ox)
                                acc[(oz * 2 + oy) * 2 + ox] =
                                    fmaf(wv, win[((oz + kz) * 4 + (oy + ky)) * 4 + ox + kx],
                                         acc[(oz * 2 + oy) * 2 + ox]);
                }
    }
#pragma unroll
    for (int o = 32; o; o >>= 1)
#pragma unroll
        for (int i = 0; i < 8; ++i) acc[i] += __shfl_xor(acc[i], o);
    if (lane == 0) {
        float m = acc[0];
#pragma unroll
        for (int i = 1; i < 8; ++i) m = fmaxf(m, acc[i]);
        out[(size_t)b * 256 + co] = fmaxf(m + bias[co], 0.f);
    }
}

// ---------------- FC head: (8,256) -> relu(128) -> 29 ----------------
__global__ void head_kernel(const float* __restrict__ v,
                            const float* __restrict__ fw1, const float* __restrict__ fb1,
                            const float* __restrict__ fw2, const float* __restrict__ fb2,
                            float* __restrict__ out) {
    int b = blockIdx.x, t = threadIdx.x;
    __shared__ float sv[256];
    __shared__ float s1[128];
    sv[t] = v[b * 256 + t];
    sv[t + 128] = v[b * 256 + t + 128];
    __syncthreads();
    float acc = fb1[t];
    const float* wr = fw1 + t * 256;
    for (int k = 0; k < 256; ++k) acc = fmaf(wr[k], sv[k], acc);
    s1[t] = fmaxf(acc, 0.f);
    __syncthreads();
    if (t < 29) {
        float a2 = fb2[t];
        const float* w2 = fw2 + t * 128;
        for (int k = 0; k < 128; ++k) a2 = fmaf(w2[k], s1[k], a2);
        out[b * 29 + t] = a2;
    }
}

extern "C" void kernel_launch(void* const* d_in, const int* in_sizes, int n_in,
                              void* d_out, int out_size, void* d_ws, size_t ws_size,
                              hipStream_t stream) {
    const float* x     = (const float*)d_in[0];
    const float* sigma = (const float*)d_in[1];
    const float* w1    = (const float*)d_in[2];
    const float* b1    = (const float*)d_in[3];
    const float* w2    = (const float*)d_in[4];
    const float* b2    = (const float*)d_in[5];
    const float* w3    = (const float*)d_in[6];
    const float* b3    = (const float*)d_in[7];
    const float* w4    = (const float*)d_in[8];
    const float* b4    = (const float*)d_in[9];
    const float* fw1   = (const float*)d_in[10];
    const float* fb1   = (const float*)d_in[11];
    const float* fw2   = (const float*)d_in[12];
    const float* fb2   = (const float*)d_in[13];
    float* out = (float*)d_out;

    float* A  = (float*)d_ws;          // 6,000,000 floats
    float* Bf = A + NVOX;              // 6,000,000 floats
    float* M0 = Bf + NVOX;             // 6*52*52
    float* M1 = M0 + NE * MP * MP;     // 6*52*52
    float* mx = M1 + NE * MP * MP;     // 1

    taps_kernel<<<1, 512, 0, stream>>>(sigma, M0, M1, mx);

    // separable blur as 3 per-plane 50x50 matmuls (scaled taps + global max in last)
    blur_mm<2, false><<<NB * NE * 50, 256, 0, stream>>>(x,  A,  M0, nullptr);
    blur_mm<1, false><<<NB * NE * 50, 256, 0, stream>>>(A,  Bf, M0, nullptr);
    blur_mm<0, true> <<<NB * NE * 50, 256, 0, stream>>>(Bf, A,  M1, mx);

    // conv1: (8,6,50^3) -> (8,32,24^3), /max folded into epilogue
    conv_wave<6, 6, 50, 24, true, false><<<dim3(216, 2, 8), 256, 0, stream>>>(A, w1, b1, mx, Bf, 32);
    // conv2: (8,32,24^3) -> (8,64,11^3)
    conv_wave<32, 32, 24, 11, false, false><<<dim3(27, 4, 8), 256, 0, stream>>>(Bf, w2, b2, nullptr, A, 64);
    // conv3: (8,64,11^3) -> partials over 8 ci-chunks (into Bf region, conv2 input dead)
    float* part = Bf;                                  // 8*8*128*512 = 4,194,304 floats
    float* pooled3 = Bf + 8 * NB * 128 * 512;          // 8*128*64 floats
    conv_wave<8, 64, 11, 4, false, true><<<dim3(8, 8, 8), 256, 0, stream>>>(A, w3, b3, nullptr, part, 128);
    pool3_kernel<8><<<256, 256, 0, stream>>>(part, b3, pooled3);
    // conv4: (8,128,4^3) -> (8,256)  (write into A; conv3 input dead)
    float* v4 = A;
    conv4_kernel<<<512, 256, 0, stream>>>(pooled3, w4, b4, v4);
    // head
    head_kernel<<<8, 128, 0, stream>>>(v4, fw1, fb1, fw2, fb2, out);
}

// Round 6
// 589.485 us; speedup vs baseline: 1.9668x; 1.2789x over previous
//
#include <hip/hip_runtime.h>
#include <math.h>

#define DIMX 50
#define KK   51
#define NE   6
#define NB   8
#define NVOX ((size_t)NB * NE * DIMX * DIMX * DIMX)  // 6,000,000
#define MP   52                                      // padded M stride

// ---------------- taps + blur matrices: M[m][e][o][c] = tap_m,e[c-o+25] ----------------
__global__ void taps_kernel(const float* __restrict__ sigma,
                            float* __restrict__ M0,  // raw taps matrix  (NE*52*52)
                            float* __restrict__ M1,  // scaled taps matrix
                            float* __restrict__ maxval) {
    __shared__ float sg[NE * KK];
    __shared__ float sgs[NE * KK];
    __shared__ float ssum[NE];
    int t = threadIdx.x;
    if (t == 0) *maxval = 0.f;
    if (t < NE * KK) {
        int e = t / KK, i = t % KK;
        float d = (float)i - 25.0f;
        float var = sigma[e] * sigma[e];
        sg[t] = expf(-d * d / (2.f * var));
    }
    __syncthreads();
    if (t < NE) {
        float s = 0.f;
        for (int i = 0; i < KK; ++i) s += sg[t * KK + i];
        ssum[t] = s;
    }
    __syncthreads();
    if (t < NE * KK) {
        int e = t / KK;
        float S = 0.f;
        for (int e2 = 0; e2 < NE; ++e2) {
            float var2 = sigma[e2] * sigma[e2];
            float a2 = 1.f / (2.f * (float)M_PI * var2);
            float se = ssum[e2];
            S += a2 * se * se * se;
        }
        float var = sigma[e] * sigma[e];
        float a = 1.f / (2.f * (float)M_PI * var);
        sgs[t] = sg[t] * (a / S);
    }
    __syncthreads();
    for (int i = t; i < 2 * NE * MP * MP; i += 512) {
        int c = i % MP, o = (i / MP) % MP, e = (i / (MP * MP)) % NE, m = i / (MP * MP * NE);
        int j = c - o + 25;
        float v = 0.f;
        if (o < 50 && c < 50 && j >= 0 && j < KK) v = (m == 0 ? sg : sgs)[e * KK + j];
        (m == 0 ? M0 : M1)[(e * MP + o) * MP + c] = v;
    }
}

// ---------------- blur pass as per-plane 50x50 matmul ----------------
template <int AXIS, bool DOMAX>
__global__ __launch_bounds__(256, 8)
void blur_mm(const float* __restrict__ in, float* __restrict__ out,
             const float* __restrict__ M, float* __restrict__ maxval) {
    __shared__ float sp[50][MP];
    const int t  = threadIdx.x;
    const int f  = blockIdx.x % 50;
    const int be = blockIdx.x / 50;
    const int e  = be % NE;
    const float* base = in + (size_t)be * 125000;
    for (int i = t; i < 2500; i += 256) {
        int hi = i / 50, lo = i % 50;
        if (AXIS == 2)      sp[hi][lo] = base[hi * 2500 + f * 50 + lo];
        else if (AXIS == 1) sp[hi][lo] = base[f * 2500 + hi * 50 + lo];
        else                sp[lo][hi] = base[f * 2500 + hi * 50 + lo];
    }
    __syncthreads();
    const int lane = t & 63;
    const int lr   = lane < 50 ? lane : 49;
    const int wv   = __builtin_amdgcn_readfirstlane(t >> 6);
    float* ob = out + (size_t)be * 125000;
    const float* Me = M + (size_t)e * MP * MP;
    float m = 0.f;
    for (int g = wv; g < 13; g += 4) {
        const int o0 = g * 4;
        const float* Mr0 = Me + (o0 + 0) * MP;
        const float* Mr1 = Me + (o0 + 1) * MP;
        const float* Mr2 = Me + (o0 + 2) * MP;
        const float* Mr3 = Me + (o0 + 3) * MP;
        float a0 = 0.f, a1 = 0.f, a2 = 0.f, a3 = 0.f;
#pragma unroll 10
        for (int c = 0; c < 50; ++c) {
            float v = sp[c][lr];
            a0 = fmaf(Mr0[c], v, a0);
            a1 = fmaf(Mr1[c], v, a1);
            a2 = fmaf(Mr2[c], v, a2);
            a3 = fmaf(Mr3[c], v, a3);
        }
        if (lane < 50) {
            float accs[4] = {a0, a1, a2, a3};
#pragma unroll
            for (int k = 0; k < 4; ++k) {
                int o = o0 + k;
                if (o < 50) {
                    size_t addr;
                    if (AXIS == 2)      addr = (size_t)o * 2500 + f * 50 + lane;
                    else if (AXIS == 1) addr = (size_t)f * 2500 + o * 50 + lane;
                    else                addr = (size_t)f * 2500 + lane * 50 + o;
                    ob[addr] = accs[k];
                    if (DOMAX) m = fmaxf(m, accs[k]);
                }
            }
        }
    }
    if (DOMAX) {
        for (int o = 32; o; o >>= 1) m = fmaxf(m, __shfl_xor(m, o));
        if ((t & 63) == 0) atomicMax((int*)maxval, __float_as_int(m));
    }
}

// ---------------- fused conv3x3x3 [+pool2+bias+relu | partial], 8 co/thread ----------------
// Block: 4^3 pooled tile x 32 co (4 waves x 8 co). Window (10^3) staged via
// global_load_lds (double-buffered, prefetch ci+1 during compute of ci, one
// __syncthreads per ci). Weights via wave-uniform scalar loads (free pipe).
template <int CIN, int CINTOT, int DIN, int DP, bool DIV, bool PARTIAL>
__global__ __launch_bounds__(256, 4)
void conv_tile8(const float* __restrict__ in, const float* __restrict__ w,
                const float* __restrict__ bias, const float* __restrict__ maxval,
                float* __restrict__ out, int COUT) {
    constexpr int NT  = (DP + 3) / 4;
    constexpr int NT3 = NT * NT * NT;
    __shared__ float swin[2][1024];

    const int t    = threadIdx.x;
    const int lane = t & 63;
    const int wave = __builtin_amdgcn_readfirstlane(t >> 6);
    const int px = lane & 3, py = (lane >> 2) & 3, pz = lane >> 4;

    const int tile  = blockIdx.x % NT3;
    const int chunk = blockIdx.x / NT3;
    const int tx = tile % NT, ty = (tile / NT) % NT, tz = tile / (NT * NT);
    const int b    = blockIdx.z;
    const int co0  = blockIdx.y * 32 + wave * 8;     // wave-uniform
    const int ci_base = chunk * CIN;

    const float* ib = in + ((size_t)b * CINTOT + ci_base) * (DIN * DIN * DIN);
    const float* wb = w + ((size_t)co0 * CINTOT + ci_base) * 27;
    const int ox0 = 8 * tx, oy0 = 8 * ty, oz0 = 8 * tz;

    // per-thread source offsets for the 4 staging dwords (dest is linear: j = s*256+t)
    int voff[4];
#pragma unroll
    for (int s = 0; s < 4; ++s) {
        int j = s * 256 + t; if (j > 999) j = 999;
        int z = j / 100, r = j % 100, y = r / 10, x = r % 10;
        int gz = oz0 + z; if (gz > DIN - 1) gz = DIN - 1;
        int gy = oy0 + y; if (gy > DIN - 1) gy = DIN - 1;
        int gx = ox0 + x; if (gx > DIN - 1) gx = DIN - 1;
        voff[s] = (gz * DIN + gy) * DIN + gx;
    }

    auto stage = [&](int ci, int bf) {
        const float* s0 = ib + (size_t)ci * (DIN * DIN * DIN);
#pragma unroll
        for (int s = 0; s < 4; ++s) {
            __builtin_amdgcn_global_load_lds(
                (const __attribute__((address_space(1))) void*)(s0 + voff[s]),
                (__attribute__((address_space(3))) void*)&swin[bf][s * 256 + wave * 64],
                4, 0, 0);
        }
    };

    float acc[8][8];
#pragma unroll
    for (int c = 0; c < 8; ++c)
#pragma unroll
        for (int i = 0; i < 8; ++i) acc[c][i] = 0.f;

    stage(0, 0);
    __syncthreads();   // drains vmcnt(0): buf0 ready

    for (int ci = 0; ci < CIN; ++ci) {
        if (ci + 1 < CIN) stage(ci + 1, (ci + 1) & 1);   // prefetch; lands during compute
        const float* cur = swin[ci & 1];
#pragma unroll
        for (int dz = 0; dz < 4; ++dz) {
            float sl[4][4];
            const float* sb = cur + (2 * pz + dz) * 100 + (2 * py) * 10 + 2 * px;
#pragma unroll
            for (int dy = 0; dy < 4; ++dy) {
                float2 q0 = *(const float2*)(sb + dy * 10);
                float2 q1 = *(const float2*)(sb + dy * 10 + 2);
                sl[dy][0] = q0.x; sl[dy][1] = q0.y; sl[dy][2] = q1.x; sl[dy][3] = q1.y;
            }
#pragma unroll
            for (int c = 0; c < 8; ++c) {
#pragma unroll
                for (int oz = 0; oz < 2; ++oz) {
                    const int kz = dz - oz;
                    if (kz < 0 || kz > 2) continue;
                    const float* wc = wb + ((size_t)c * CINTOT + ci) * 27 + kz * 9;
#pragma unroll
                    for (int ky = 0; ky < 3; ++ky)
#pragma unroll
                        for (int kx = 0; kx < 3; ++kx) {
                            float wv = wc[ky * 3 + kx];
#pragma unroll
                            for (int oy = 0; oy < 2; ++oy)
#pragma unroll
                                for (int ox = 0; ox < 2; ++ox)
                                    acc[c][oz * 4 + oy * 2 + ox] =
                                        fmaf(wv, sl[oy + ky][ox + kx], acc[c][oz * 4 + oy * 2 + ox]);
                        }
                }
            }
        }
        __syncthreads();   // all waves done reading cur; prefetched loads drained
    }

    if constexpr (PARTIAL) {
#pragma unroll
        for (int c = 0; c < 8; ++c) {
            size_t base = (((size_t)chunk * NB + b) * (size_t)COUT + (co0 + c)) * 512 + (size_t)lane * 8;
#pragma unroll
            for (int i = 0; i < 8; ++i) out[base + i] = acc[c][i];
        }
    } else {
        const int qx = tx * 4 + px, qy = ty * 4 + py, qz = tz * 4 + pz;
        if (qx < DP && qy < DP && qz < DP) {
            float mv = DIV ? *maxval : 1.f;
#pragma unroll
            for (int c = 0; c < 8; ++c) {
                float m = acc[c][0];
#pragma unroll
                for (int i = 1; i < 8; ++i) m = fmaxf(m, acc[c][i]);
                float o = DIV ? (m / mv + bias[co0 + c]) : (m + bias[co0 + c]);
                out[((size_t)b * COUT + (co0 + c)) * (DP * DP * DP) + (qz * DP + qy) * DP + qx] =
                    fmaxf(o, 0.f);
            }
        }
    }
}

// ---------------- conv3 chunk-reduce + pool + bias + relu ----------------
template <int NCH>
__global__ void pool3_kernel(const float* __restrict__ part, const float* __restrict__ bias,
                             float* __restrict__ out) {
    int idx = blockIdx.x * 256 + threadIdx.x;  // 8*128*64
    if (idx >= NB * 128 * 64) return;
    int vox = idx & 63;
    int co  = (idx >> 6) & 127;
    int b   = idx >> 13;
    float s[8];
#pragma unroll
    for (int i = 0; i < 8; ++i) s[i] = 0.f;
#pragma unroll
    for (int ch = 0; ch < NCH; ++ch) {
        const float* p = part + (((size_t)ch * NB + b) * 128 + co) * 512 + (size_t)vox * 8;
#pragma unroll
        for (int i = 0; i < 8; ++i) s[i] += p[i];
    }
    float m = s[0];
#pragma unroll
    for (int i = 1; i < 8; ++i) m = fmaxf(m, s[i]);
    out[((size_t)b * 128 + co) * 64 + vox] = fmaxf(m + bias[co], 0.f);
}

// ---------------- conv4: Cin=128, Din=4 -> conv 2^3 -> pool 1; wave per (b,co) ----------------
__global__ void conv4_kernel(const float* __restrict__ in, const float* __restrict__ w,
                             const float* __restrict__ bias, float* __restrict__ out) {
    int wid = (int)((blockIdx.x * blockDim.x + threadIdx.x) >> 6);
    int lane = threadIdx.x & 63;
    if (wid >= NB * 256) return;
    int b = wid >> 8, co = wid & 255;
    float acc[8];
#pragma unroll
    for (int i = 0; i < 8; ++i) acc[i] = 0.f;
    for (int half = 0; half < 2; ++half) {
        int ci = lane + half * 64;
        const float* cb = in + ((size_t)b * 128 + ci) * 64;
        float win[64];
        const float4* c4 = (const float4*)cb;
#pragma unroll
        for (int i = 0; i < 16; ++i) {
            float4 v = c4[i];
            win[4 * i + 0] = v.x; win[4 * i + 1] = v.y;
            win[4 * i + 2] = v.z; win[4 * i + 3] = v.w;
        }
        const float* wc = w + ((size_t)co * 128 + ci) * 27;
        float wr[27];
#pragma unroll
        for (int i = 0; i < 27; ++i) wr[i] = wc[i];
#pragma unroll
        for (int kz = 0; kz < 3; ++kz)
#pragma unroll
            for (int ky = 0; ky < 3; ++ky)
#pragma unroll
                for (int kx = 0; kx < 3; ++kx) {
                    float wv = wr[(kz * 3 + ky) * 3 + kx];
#pragma unroll
                    for (int oz = 0; oz < 2; ++oz)
#pragma unroll
                        for (int oy = 0; oy < 2; ++oy)
#pragma unroll
                            for (int ox = 0; ox < 2; ++ox)
                                acc[(oz * 2 + oy) * 2 + ox] =
                                    fmaf(wv, win[((oz + kz) * 4 + (oy + ky)) * 4 + ox + kx],
                                         acc[(oz * 2 + oy) * 2 + ox]);
                }
    }
#pragma unroll
    for (int o = 32; o; o >>= 1)
#pragma unroll
        for (int i = 0; i < 8; ++i) acc[i] += __shfl_xor(acc[i], o);
    if (lane == 0) {
        float m = acc[0];
#pragma unroll
        for (int i = 1; i < 8; ++i) m = fmaxf(m, acc[i]);
        out[(size_t)b * 256 + co] = fmaxf(m + bias[co], 0.f);
    }
}

// ---------------- FC head: (8,256) -> relu(128) -> 29 ----------------
__global__ void head_kernel(const float* __restrict__ v,
                            const float* __restrict__ fw1, const float* __restrict__ fb1,
                            const float* __restrict__ fw2, const float* __restrict__ fb2,
                            float* __restrict__ out) {
    int b = blockIdx.x, t = threadIdx.x;
    __shared__ float sv[256];
    __shared__ float s1[128];
    sv[t] = v[b * 256 + t];
    sv[t + 128] = v[b * 256 + t + 128];
    __syncthreads();
    float acc = fb1[t];
    const float* wr = fw1 + t * 256;
    for (int k = 0; k < 256; ++k) acc = fmaf(wr[k], sv[k], acc);
    s1[t] = fmaxf(acc, 0.f);
    __syncthreads();
    if (t < 29) {
        float a2 = fb2[t];
        const float* w2 = fw2 + t * 128;
        for (int k = 0; k < 128; ++k) a2 = fmaf(w2[k], s1[k], a2);
        out[b * 29 + t] = a2;
    }
}

extern "C" void kernel_launch(void* const* d_in, const int* in_sizes, int n_in,
                              void* d_out, int out_size, void* d_ws, size_t ws_size,
                              hipStream_t stream) {
    const float* x     = (const float*)d_in[0];
    const float* sigma = (const float*)d_in[1];
    const float* w1    = (const float*)d_in[2];
    const float* b1    = (const float*)d_in[3];
    const float* w2    = (const float*)d_in[4];
    const float* b2    = (const float*)d_in[5];
    const float* w3    = (const float*)d_in[6];
    const float* b3    = (const float*)d_in[7];
    const float* w4    = (const float*)d_in[8];
    const float* b4    = (const float*)d_in[9];
    const float* fw1   = (const float*)d_in[10];
    const float* fb1   = (const float*)d_in[11];
    const float* fw2   = (const float*)d_in[12];
    const float* fb2   = (const float*)d_in[13];
    float* out = (float*)d_out;

    float* A  = (float*)d_ws;          // 6,000,000 floats
    float* Bf = A + NVOX;              // 6,000,000 floats
    float* M0 = Bf + NVOX;             // 6*52*52
    float* M1 = M0 + NE * MP * MP;     // 6*52*52
    float* mx = M1 + NE * MP * MP;     // 1

    taps_kernel<<<1, 512, 0, stream>>>(sigma, M0, M1, mx);

    // separable blur as 3 per-plane 50x50 matmuls (scaled taps + global max in last)
    blur_mm<2, false><<<NB * NE * 50, 256, 0, stream>>>(x,  A,  M0, nullptr);
    blur_mm<1, false><<<NB * NE * 50, 256, 0, stream>>>(A,  Bf, M0, nullptr);
    blur_mm<0, true> <<<NB * NE * 50, 256, 0, stream>>>(Bf, A,  M1, mx);

    // conv1: (8,6,50^3) -> (8,32,24^3), /max folded into epilogue
    conv_tile8<6, 6, 50, 24, true, false><<<dim3(216, 1, 8), 256, 0, stream>>>(A, w1, b1, mx, Bf, 32);
    // conv2: (8,32,24^3) -> (8,64,11^3)
    conv_tile8<32, 32, 24, 11, false, false><<<dim3(27, 2, 8), 256, 0, stream>>>(Bf, w2, b2, nullptr, A, 64);
    // conv3: (8,64,11^3) -> partials over 8 ci-chunks (into Bf region, conv2 input dead)
    float* part = Bf;                                  // 8*8*128*512 = 4,194,304 floats
    float* pooled3 = Bf + 8 * NB * 128 * 512;          // 8*128*64 floats
    conv_tile8<8, 64, 11, 4, false, true><<<dim3(8, 4, 8), 256, 0, stream>>>(A, w3, b3, nullptr, part, 128);
    pool3_kernel<8><<<256, 256, 0, stream>>>(part, b3, pooled3);
    // conv4: (8,128,4^3) -> (8,256)  (write into A; conv3 input dead)
    float* v4 = A;
    conv4_kernel<<<512, 256, 0, stream>>>(pooled3, w4, b4, v4);
    // head
    head_kernel<<<8, 128, 0, stream>>>(v4, fw1, fb1, fw2, fb2, out);
}

// Round 7
// 515.063 us; speedup vs baseline: 2.2510x; 1.1445x over previous
//
#include <hip/hip_runtime.h>
#include <math.h>

#define DIMX 50
#define KK   51
#define NE   6
#define NB   8
#define NVOX ((size_t)NB * NE * DIMX * DIMX * DIMX)  // 6,000,000
#define MP   52                                      // padded M stride

// ---------------- taps + blur matrices: M[m][e][o][c] = tap_m,e[c-o+25] ----------------
__global__ void taps_kernel(const float* __restrict__ sigma,
                            float* __restrict__ M0,  // raw taps matrix  (NE*52*52)
                            float* __restrict__ M1,  // scaled taps matrix
                            float* __restrict__ maxval) {
    __shared__ float sg[NE * KK];
    __shared__ float sgs[NE * KK];
    __shared__ float ssum[NE];
    int t = threadIdx.x;
    if (t == 0) *maxval = 0.f;
    if (t < NE * KK) {
        int e = t / KK, i = t % KK;
        float d = (float)i - 25.0f;
        float var = sigma[e] * sigma[e];
        sg[t] = expf(-d * d / (2.f * var));
    }
    __syncthreads();
    if (t < NE) {
        float s = 0.f;
        for (int i = 0; i < KK; ++i) s += sg[t * KK + i];
        ssum[t] = s;
    }
    __syncthreads();
    if (t < NE * KK) {
        int e = t / KK;
        float S = 0.f;
        for (int e2 = 0; e2 < NE; ++e2) {
            float var2 = sigma[e2] * sigma[e2];
            float a2 = 1.f / (2.f * (float)M_PI * var2);
            float se = ssum[e2];
            S += a2 * se * se * se;
        }
        float var = sigma[e] * sigma[e];
        float a = 1.f / (2.f * (float)M_PI * var);
        sgs[t] = sg[t] * (a / S);
    }
    __syncthreads();
    for (int i = t; i < 2 * NE * MP * MP; i += 512) {
        int c = i % MP, o = (i / MP) % MP, e = (i / (MP * MP)) % NE, m = i / (MP * MP * NE);
        int j = c - o + 25;
        float v = 0.f;
        if (o < 50 && c < 50 && j >= 0 && j < KK) v = (m == 0 ? sg : sgs)[e * KK + j];
        (m == 0 ? M0 : M1)[(e * MP + o) * MP + c] = v;
    }
}

// ---------------- blur pass as per-plane 50x50 matmul ----------------
template <int AXIS, bool DOMAX>
__global__ __launch_bounds__(256, 8)
void blur_mm(const float* __restrict__ in, float* __restrict__ out,
             const float* __restrict__ M, float* __restrict__ maxval) {
    __shared__ float sp[50][MP];
    const int t  = threadIdx.x;
    const int f  = blockIdx.x % 50;
    const int be = blockIdx.x / 50;
    const int e  = be % NE;
    const float* base = in + (size_t)be * 125000;
    for (int i = t; i < 2500; i += 256) {
        int hi = i / 50, lo = i % 50;
        if (AXIS == 2)      sp[hi][lo] = base[hi * 2500 + f * 50 + lo];
        else if (AXIS == 1) sp[hi][lo] = base[f * 2500 + hi * 50 + lo];
        else                sp[lo][hi] = base[f * 2500 + hi * 50 + lo];
    }
    __syncthreads();
    const int lane = t & 63;
    const int lr   = lane < 50 ? lane : 49;
    const int wv   = __builtin_amdgcn_readfirstlane(t >> 6);
    float* ob = out + (size_t)be * 125000;
    const float* Me = M + (size_t)e * MP * MP;
    float m = 0.f;
    for (int g = wv; g < 13; g += 4) {
        const int o0 = g * 4;
        const float* Mr0 = Me + (o0 + 0) * MP;
        const float* Mr1 = Me + (o0 + 1) * MP;
        const float* Mr2 = Me + (o0 + 2) * MP;
        const float* Mr3 = Me + (o0 + 3) * MP;
        float a0 = 0.f, a1 = 0.f, a2 = 0.f, a3 = 0.f;
#pragma unroll 10
        for (int c = 0; c < 50; ++c) {
            float v = sp[c][lr];
            a0 = fmaf(Mr0[c], v, a0);
            a1 = fmaf(Mr1[c], v, a1);
            a2 = fmaf(Mr2[c], v, a2);
            a3 = fmaf(Mr3[c], v, a3);
        }
        if (lane < 50) {
            float accs[4] = {a0, a1, a2, a3};
#pragma unroll
            for (int k = 0; k < 4; ++k) {
                int o = o0 + k;
                if (o < 50) {
                    size_t addr;
                    if (AXIS == 2)      addr = (size_t)o * 2500 + f * 50 + lane;
                    else if (AXIS == 1) addr = (size_t)f * 2500 + o * 50 + lane;
                    else                addr = (size_t)f * 2500 + lane * 50 + o;
                    ob[addr] = accs[k];
                    if (DOMAX) m = fmaxf(m, accs[k]);
                }
            }
        }
    }
    if (DOMAX) {
        for (int o = 32; o; o >>= 1) m = fmaxf(m, __shfl_xor(m, o));
        if ((t & 63) == 0) atomicMax((int*)maxval, __float_as_int(m));
    }
}

// ---------------- fused conv3x3x3 [+pool2+bias+relu | partial], 8 co/thread ----------------
// Block: 4^3 pooled tile x 32 co (4 waves x 8 co). NCI channels staged per phase via
// global_load_lds, double-buffered across phases. LDS window layout [z][y][even/odd][6]
// (row stride 12, e/o split) -> per-lane read offset 16*pz+24*py+px: 2-way banks (free).
// Weights via wave-uniform scalar loads (free pipe).
template <int NCI, int NPHASE, int CINTOT, int DIN, int DP, bool DIV, bool PARTIAL>
__global__ __launch_bounds__(256, 2)
void conv_phase(const float* __restrict__ in, const float* __restrict__ w,
                const float* __restrict__ bias, const float* __restrict__ maxval,
                float* __restrict__ out, int COUT) {
    constexpr int DIN3 = DIN * DIN * DIN;
    constexpr int NT   = (DP + 3) / 4;
    constexpr int NT3  = NT * NT * NT;
    constexpr int CWORDS = 1200;             // [10][10][12] per ci
    constexpr int NBUF = (NPHASE > 1) ? 2 : 1;
    __shared__ float swin[NBUF][NCI * CWORDS];

    const int t    = threadIdx.x;
    const int lane = t & 63;
    const int wave = __builtin_amdgcn_readfirstlane(t >> 6);
    const int px = lane & 3, py = (lane >> 2) & 3, pz = lane >> 4;

    const int tile  = blockIdx.x % NT3;
    const int chunk = blockIdx.x / NT3;
    const int tx = tile % NT, ty = (tile / NT) % NT, tz = tile / (NT * NT);
    const int b    = blockIdx.z;
    const int co0  = blockIdx.y * 32 + wave * 8;     // wave-uniform
    const int ci_base = chunk * NCI * NPHASE;

    const float* ib = in + ((size_t)b * CINTOT + ci_base) * DIN3;
    const float* wb = w + ((size_t)co0 * CINTOT + ci_base) * 27;
    const int ox0 = 8 * tx, oy0 = 8 * ty, oz0 = 8 * tz;

    // per-thread source offsets; LDS dest is linear j = s*256 + t, source pre-permuted
    int off[5];
#pragma unroll
    for (int s = 0; s < 5; ++s) {
        int j = s * 256 + t; if (j >= CWORDS) j = CWORDS - 1;
        int z = j / 120, r = j % 120, y = r / 12, q = r % 12;
        int x = 2 * (q % 6) + q / 6; if (x > 9) x = 9;   // e/o split; xe=5 slack never read
        int gz = oz0 + z; if (gz > DIN - 1) gz = DIN - 1;
        int gy = oy0 + y; if (gy > DIN - 1) gy = DIN - 1;
        int gx = ox0 + x; if (gx > DIN - 1) gx = DIN - 1;
        off[s] = (gz * DIN + gy) * DIN + gx;
    }

    auto stage = [&](int p, int bf) {
        const float* s0 = ib + (size_t)p * NCI * DIN3;
#pragma unroll
        for (int ci = 0; ci < NCI; ++ci) {
            const float* sc = s0 + (size_t)ci * DIN3;
            float* db = &swin[bf][ci * CWORDS];
#pragma unroll
            for (int s = 0; s < 4; ++s)
                __builtin_amdgcn_global_load_lds(
                    (const __attribute__((address_space(1))) void*)(sc + off[s]),
                    (__attribute__((address_space(3))) void*)(db + s * 256 + wave * 64),
                    4, 0, 0);
            if (t < CWORDS - 1024)   // tail: exec-masked lanes don't write
                __builtin_amdgcn_global_load_lds(
                    (const __attribute__((address_space(1))) void*)(sc + off[4]),
                    (__attribute__((address_space(3))) void*)(db + 1024 + wave * 64),
                    4, 0, 0);
        }
    };

    float acc[8][8];
#pragma unroll
    for (int c = 0; c < 8; ++c)
#pragma unroll
        for (int i = 0; i < 8; ++i) acc[c][i] = 0.f;

    stage(0, 0);
    __syncthreads();

#pragma unroll 1
    for (int p = 0; p < NPHASE; ++p) {
        if (p + 1 < NPHASE) stage(p + 1, (p + 1) & 1);   // prefetch into other buffer
        const float* pb = &swin[(NBUF > 1) ? (p & 1) : 0][0];
#pragma unroll 1
        for (int ci = 0; ci < NCI; ++ci) {
            const float* cb = pb + ci * CWORDS;
#pragma unroll
            for (int dz = 0; dz < 4; ++dz) {
                const float* sb = cb + (2 * pz + dz) * 120 + (2 * py) * 12 + px;
                float sl[4][4];
#pragma unroll
                for (int dy = 0; dy < 4; ++dy) {
                    sl[dy][0] = sb[dy * 12];
                    sl[dy][1] = sb[dy * 12 + 6];
                    sl[dy][2] = sb[dy * 12 + 1];
                    sl[dy][3] = sb[dy * 12 + 7];
                }
#pragma unroll
                for (int c = 0; c < 8; ++c) {
#pragma unroll
                    for (int oz = 0; oz < 2; ++oz) {
                        const int kz = dz - oz;
                        if (kz < 0 || kz > 2) continue;
                        const float* wc = wb + ((size_t)c * CINTOT + p * NCI + ci) * 27 + kz * 9;
#pragma unroll
                        for (int ky = 0; ky < 3; ++ky)
#pragma unroll
                            for (int kx = 0; kx < 3; ++kx) {
                                float wv = wc[ky * 3 + kx];
#pragma unroll
                                for (int oy = 0; oy < 2; ++oy)
#pragma unroll
                                    for (int ox = 0; ox < 2; ++ox)
                                        acc[c][oz * 4 + oy * 2 + ox] =
                                            fmaf(wv, sl[oy + ky][ox + kx],
                                                 acc[c][oz * 4 + oy * 2 + ox]);
                            }
                    }
                }
            }
        }
        __syncthreads();
    }

    if constexpr (PARTIAL) {
#pragma unroll
        for (int c = 0; c < 8; ++c) {
            size_t base = (((size_t)chunk * NB + b) * (size_t)COUT + (co0 + c)) * 512 + (size_t)lane * 8;
#pragma unroll
            for (int i = 0; i < 8; ++i) out[base + i] = acc[c][i];
        }
    } else {
        const int qx = tx * 4 + px, qy = ty * 4 + py, qz = tz * 4 + pz;
        if (qx < DP && qy < DP && qz < DP) {
            float mv = DIV ? *maxval : 1.f;
#pragma unroll
            for (int c = 0; c < 8; ++c) {
                float m = acc[c][0];
#pragma unroll
                for (int i = 1; i < 8; ++i) m = fmaxf(m, acc[c][i]);
                float o = DIV ? (m / mv + bias[co0 + c]) : (m + bias[co0 + c]);
                out[((size_t)b * COUT + (co0 + c)) * (DP * DP * DP) + (qz * DP + qy) * DP + qx] =
                    fmaxf(o, 0.f);
            }
        }
    }
}

// ---------------- conv3 chunk-reduce + pool + bias + relu ----------------
template <int NCH>
__global__ void pool3_kernel(const float* __restrict__ part, const float* __restrict__ bias,
                             float* __restrict__ out) {
    int idx = blockIdx.x * 256 + threadIdx.x;  // 8*128*64
    if (idx >= NB * 128 * 64) return;
    int vox = idx & 63;
    int co  = (idx >> 6) & 127;
    int b   = idx >> 13;
    float s[8];
#pragma unroll
    for (int i = 0; i < 8; ++i) s[i] = 0.f;
#pragma unroll
    for (int ch = 0; ch < NCH; ++ch) {
        const float* p = part + (((size_t)ch * NB + b) * 128 + co) * 512 + (size_t)vox * 8;
#pragma unroll
        for (int i = 0; i < 8; ++i) s[i] += p[i];
    }
    float m = s[0];
#pragma unroll
    for (int i = 1; i < 8; ++i) m = fmaxf(m, s[i]);
    out[((size_t)b * 128 + co) * 64 + vox] = fmaxf(m + bias[co], 0.f);
}

// ---------------- conv4: Cin=128, Din=4 -> conv 2^3 -> pool 1; wave per (b,co) ----------------
__global__ void conv4_kernel(const float* __restrict__ in, const float* __restrict__ w,
                             const float* __restrict__ bias, float* __restrict__ out) {
    int wid = (int)((blockIdx.x * blockDim.x + threadIdx.x) >> 6);
    int lane = threadIdx.x & 63;
    if (wid >= NB * 256) return;
    int b = wid >> 8, co = wid & 255;
    float acc[8];
#pragma unroll
    for (int i = 0; i < 8; ++i) acc[i] = 0.f;
    for (int half = 0; half < 2; ++half) {
        int ci = lane + half * 64;
        const float* cb = in + ((size_t)b * 128 + ci) * 64;
        float win[64];
        const float4* c4 = (const float4*)cb;
#pragma unroll
        for (int i = 0; i < 16; ++i) {
            float4 v = c4[i];
            win[4 * i + 0] = v.x; win[4 * i + 1] = v.y;
            win[4 * i + 2] = v.z; win[4 * i + 3] = v.w;
        }
        const float* wc = w + ((size_t)co * 128 + ci) * 27;
        float wr[27];
#pragma unroll
        for (int i = 0; i < 27; ++i) wr[i] = wc[i];
#pragma unroll
        for (int kz = 0; kz < 3; ++kz)
#pragma unroll
            for (int ky = 0; ky < 3; ++ky)
#pragma unroll
                for (int kx = 0; kx < 3; ++kx) {
                    float wv = wr[(kz * 3 + ky) * 3 + kx];
#pragma unroll
                    for (int oz = 0; oz < 2; ++oz)
#pragma unroll
                        for (int oy = 0; oy < 2; ++oy)
#pragma unroll
                            for (int ox = 0; ox < 2; ++ox)
                                acc[(oz * 2 + oy) * 2 + ox] =
                                    fmaf(wv, win[((oz + kz) * 4 + (oy + ky)) * 4 + ox + kx],
                                         acc[(oz * 2 + oy) * 2 + ox]);
                }
    }
#pragma unroll
    for (int o = 32; o; o >>= 1)
#pragma unroll
        for (int i = 0; i < 8; ++i) acc[i] += __shfl_xor(acc[i], o);
    if (lane == 0) {
        float m = acc[0];
#pragma unroll
        for (int i = 1; i < 8; ++i) m = fmaxf(m, acc[i]);
        out[(size_t)b * 256 + co] = fmaxf(m + bias[co], 0.f);
    }
}

// ---------------- FC head: (8,256) -> relu(128) -> 29 ----------------
__global__ void head_kernel(const float* __restrict__ v,
                            const float* __restrict__ fw1, const float* __restrict__ fb1,
                            const float* __restrict__ fw2, const float* __restrict__ fb2,
                            float* __restrict__ out) {
    int b = blockIdx.x, t = threadIdx.x;
    __shared__ float sv[256];
    __shared__ float s1[128];
    sv[t] = v[b * 256 + t];
    sv[t + 128] = v[b * 256 + t + 128];
    __syncthreads();
    float acc = fb1[t];
    const float* wr = fw1 + t * 256;
    for (int k = 0; k < 256; ++k) acc = fmaf(wr[k], sv[k], acc);
    s1[t] = fmaxf(acc, 0.f);
    __syncthreads();
    if (t < 29) {
        float a2 = fb2[t];
        const float* w2 = fw2 + t * 128;
        for (int k = 0; k < 128; ++k) a2 = fmaf(w2[k], s1[k], a2);
        out[b * 29 + t] = a2;
    }
}

extern "C" void kernel_launch(void* const* d_in, const int* in_sizes, int n_in,
                              void* d_out, int out_size, void* d_ws, size_t ws_size,
                              hipStream_t stream) {
    const float* x     = (const float*)d_in[0];
    const float* sigma = (const float*)d_in[1];
    const float* w1    = (const float*)d_in[2];
    const float* b1    = (const float*)d_in[3];
    const float* w2    = (const float*)d_in[4];
    const float* b2    = (const float*)d_in[5];
    const float* w3    = (const float*)d_in[6];
    const float* b3    = (const float*)d_in[7];
    const float* w4    = (const float*)d_in[8];
    const float* b4    = (const float*)d_in[9];
    const float* fw1   = (const float*)d_in[10];
    const float* fb1   = (const float*)d_in[11];
    const float* fw2   = (const float*)d_in[12];
    const float* fb2   = (const float*)d_in[13];
    float* out = (float*)d_out;

    float* A  = (float*)d_ws;          // 6,000,000 floats
    float* Bf = A + NVOX;              // 6,000,000 floats
    float* M0 = Bf + NVOX;             // 6*52*52
    float* M1 = M0 + NE * MP * MP;     // 6*52*52
    float* mx = M1 + NE * MP * MP;     // 1

    taps_kernel<<<1, 512, 0, stream>>>(sigma, M0, M1, mx);

    // separable blur as 3 per-plane 50x50 matmuls (scaled taps + global max in last)
    blur_mm<2, false><<<NB * NE * 50, 256, 0, stream>>>(x,  A,  M0, nullptr);
    blur_mm<1, false><<<NB * NE * 50, 256, 0, stream>>>(A,  Bf, M0, nullptr);
    blur_mm<0, true> <<<NB * NE * 50, 256, 0, stream>>>(Bf, A,  M1, mx);

    // conv1: (8,6,50^3) -> (8,32,24^3), /max folded into epilogue; 2 phases x 3 ci
    conv_phase<3, 2, 6, 50, 24, true, false><<<dim3(216, 1, 8), 256, 0, stream>>>(A, w1, b1, mx, Bf, 32);
    // conv2: (8,32,24^3) -> (8,64,11^3); 8 phases x 4 ci
    conv_phase<4, 8, 32, 24, 11, false, false><<<dim3(27, 2, 8), 256, 0, stream>>>(Bf, w2, b2, nullptr, A, 64);
    // conv3: (8,64,11^3) -> partials over 8 ci-chunks (2 phases x 4 ci each)
    float* part = Bf;                                  // 8*8*128*512 = 4,194,304 floats
    float* pooled3 = Bf + 8 * NB * 128 * 512;          // 8*128*64 floats
    conv_phase<4, 2, 64, 11, 4, false, true><<<dim3(8, 4, 8), 256, 0, stream>>>(A, w3, b3, nullptr, part, 128);
    pool3_kernel<8><<<256, 256, 0, stream>>>(part, b3, pooled3);
    // conv4: (8,128,4^3) -> (8,256)  (write into A; conv3 input dead)
    float* v4 = A;
    conv4_kernel<<<512, 256, 0, stream>>>(pooled3, w4, b4, v4);
    // head
    head_kernel<<<8, 128, 0, stream>>>(v4, fw1, fb1, fw2, fb2, out);
}